// Round 1
// baseline (1844.902 us; speedup 1.0000x reference)
//
#include <hip/hip_runtime.h>
#include <hip/hip_bf16.h>

typedef _Float16 f16;
typedef __attribute__((ext_vector_type(8))) _Float16 half8;
typedef __attribute__((ext_vector_type(4))) float f32x4;

// ---------------------------------------------------------------------------
// problem constants
static const int BN = 16, SEQN = 4000;

// ---------------------------------------------------------------------------
// simple casts / packs
__global__ void k_cast_f16(const float* __restrict__ in, f16* __restrict__ out, int n) {
  int i = blockIdx.x * blockDim.x + threadIdx.x;
  int stride = gridDim.x * blockDim.x;
  for (; i < n; i += stride) out[i] = (f16)in[i];
}

// out[s][f*800+g] = w_local[s][g*5+f]   (column permutation so K matches conv output)
__global__ void k_pack_wlocal(const float* __restrict__ in, f16* __restrict__ out) {
  int i = blockIdx.x * blockDim.x + threadIdx.x;
  int stride = gridDim.x * blockDim.x;
  const int n = 4000 * 4000;
  for (; i < n; i += stride) {
    int s = i / 4000, k = i % 4000;
    int f = k / 800, g = k % 800;
    out[i] = (f16)in[s * 4000 + g * 5 + f];
  }
}

// out[c*ldo + r] = in[r*C + c] * scale
__global__ void k_transpose_cast(const float* __restrict__ in, f16* __restrict__ out,
                                 int R, int C, int ldo, float scale) {
  __shared__ float tile[32][33];
  int c0 = blockIdx.x * 32, r0 = blockIdx.y * 32;
  for (int i = threadIdx.y; i < 32; i += 8) {
    int r = r0 + i, c = c0 + threadIdx.x;
    tile[i][threadIdx.x] = (r < R && c < C) ? in[(long)r * C + c] : 0.f;
  }
  __syncthreads();
  for (int i = threadIdx.y; i < 32; i += 8) {
    int c = c0 + i, r = r0 + threadIdx.x;
    if (c < C && r < R) out[(long)c * ldo + r] = (f16)(tile[threadIdx.x][i] * scale);
  }
}

// ---------------------------------------------------------------------------
// embedding gather + D-scale -> padded branch inputs (f16) + lsp fp32 (residual)
// pad layout: [g(800)][fpad(7)][b(16)][epad(W+2)], zero borders (pre-memset)
__global__ void k_gather(const int* __restrict__ X, const float* __restrict__ emb,
                         f16* __restrict__ pad_lsp, f16* __restrict__ pad_pit,
                         f16* __restrict__ pad_cod, f16* __restrict__ pad_gai,
                         float* __restrict__ lsp32) {
  const float scale[15] = {1.f,1.f,1.f,1.f,0.8f,0.512f,0.8f,0.64f,0.512f,0.64f,0.512f,0.8f,0.64f,0.512f,0.512f};
  const int br[15] = {0,0,0,0,1,1,2,2,3,3,1,2,2,3,3};
  const int po[15] = {0,1,2,3,0,1,0,1,0,2,2,2,3,1,3};
  int id = blockIdx.x * blockDim.x + threadIdx.x;
  if (id >= BN * SEQN) return;
  int b = id / SEQN, s = id % SEQN;
  int g = s / 5, f = s % 5;
  const int* xr = X + (long)id * 15;
  f16* pads[4] = {pad_lsp, pad_pit, pad_cod, pad_gai};
  const int wpad[4] = {42, 32, 42, 42};
#pragma unroll
  for (int c = 0; c < 15; c++) {
    int idx = xr[c];
    const float* er = emb + (long)idx * 10;
    const int t = br[c], p = po[c];
    f16* base = pads[t] + ((long)(g * 7 + (f + 1)) * 16 + b) * wpad[t] + 1 + p * 10;
#pragma unroll
    for (int j = 0; j < 10; j++) {
      float v = er[j] * scale[c];
      base[j] = (f16)v;
      if (t == 0) lsp32[((long)b * SEQN + s) * 40 + p * 10 + j] = v;
    }
  }
}

// ---------------------------------------------------------------------------
// im2col: col[m=(f,b,e)][k=g*9+(df*3+de)] = pad[g][f+df][b][e+de]; zeros for m>=Mreal
__global__ void k_im2col(const f16* __restrict__ pad, f16* __restrict__ col,
                         int W, int Mreal, int Mpad) {
  int id = blockIdx.x * blockDim.x + threadIdx.x;
  int total = Mpad * 800;
  if (id >= total) return;
  int m = id / 800, gp = id % 800;
  f16* out = col + (long)m * 7200 + gp * 9;
  if (m >= Mreal) {
#pragma unroll
    for (int j = 0; j < 9; j++) out[j] = (f16)0.f;
    return;
  }
  int W16 = 16 * W;
  int f = m / W16, r = m % W16, b = r / W, e = r % W;
  int wp = W + 2;
  const f16* src = pad + ((long)(gp * 7 + f) * 16 + b) * wp + e;
#pragma unroll
  for (int df = 0; df < 3; df++)
#pragma unroll
    for (int de = 0; de < 3; de++)
      out[df * 3 + de] = src[df * 16 * wp + de];
}

// ---------------------------------------------------------------------------
// NT GEMM: C[m][n] = sum_k A[m*lda+k]*B[n*ldb+k], fp16 in / fp32 acc
// OUTM: 0 = fp32 plain, 2 = f16 conv-permuted store ((b*W+e)*4000 + f*800 + n)
// BIASM: 0 none, 1 bias[m], 2 bias[n]
template <int OUTM, int BIASM>
__global__ __launch_bounds__(256) void k_gemm(
    const f16* __restrict__ A, int lda, const f16* __restrict__ Bm, int ldb,
    void* __restrict__ Cout, int ldc, const float* __restrict__ bias,
    int K, int Mreal, int Nreal, int Wout) {
  __shared__ __align__(16) f16 As[128 * 40];
  __shared__ __align__(16) f16 Bs[128 * 40];
  int m0 = blockIdx.y * 128, n0 = blockIdx.x * 128;
  int t = threadIdx.x;
  int lane = t & 63, wv = t >> 6;
  int wm = (wv >> 1) * 64, wn = (wv & 1) * 64;
  int l15 = lane & 15, kg = lane >> 4;
  int srow = t & 127, shalf = t >> 7;

  const f16* Ag = A + (long)(m0 + srow) * lda + shalf * 16;
  const f16* Bg = Bm + (long)(n0 + srow) * ldb + shalf * 16;

  f32x4 acc[4][4] = {};
  int KT = K >> 5;
  f32x4 a0, a1, b0, b1;
  a0 = *(const f32x4*)(Ag); a1 = *(const f32x4*)(Ag + 8);
  b0 = *(const f32x4*)(Bg); b1 = *(const f32x4*)(Bg + 8);

  for (int kt = 0; kt < KT; kt++) {
    __syncthreads();
    *(f32x4*)(&As[srow * 40 + shalf * 16]) = a0;
    *(f32x4*)(&As[srow * 40 + shalf * 16 + 8]) = a1;
    *(f32x4*)(&Bs[srow * 40 + shalf * 16]) = b0;
    *(f32x4*)(&Bs[srow * 40 + shalf * 16 + 8]) = b1;
    __syncthreads();
    if (kt + 1 < KT) {
      const f16* ap = Ag + (kt + 1) * 32;
      const f16* bp = Bg + (kt + 1) * 32;
      a0 = *(const f32x4*)ap; a1 = *(const f32x4*)(ap + 8);
      b0 = *(const f32x4*)bp; b1 = *(const f32x4*)(bp + 8);
    }
    half8 av[4], bv[4];
#pragma unroll
    for (int i = 0; i < 4; i++) {
      av[i] = *(const half8*)(&As[(wm + i * 16 + l15) * 40 + kg * 8]);
      bv[i] = *(const half8*)(&Bs[(wn + i * 16 + l15) * 40 + kg * 8]);
    }
#pragma unroll
    for (int i = 0; i < 4; i++)
#pragma unroll
      for (int j = 0; j < 4; j++)
        acc[i][j] = __builtin_amdgcn_mfma_f32_16x16x32_f16(av[i], bv[j], acc[i][j], 0, 0, 0);
  }

#pragma unroll
  for (int i = 0; i < 4; i++) {
    int mb = m0 + wm + i * 16 + kg * 4;
#pragma unroll
    for (int j = 0; j < 4; j++) {
      int n = n0 + wn + j * 16 + l15;
      f32x4 d = acc[i][j];
#pragma unroll
      for (int r = 0; r < 4; r++) {
        int m = mb + r;
        if (m >= Mreal || n >= Nreal) continue;
        float val = d[r];
        if (BIASM == 1) val += bias[m];
        if (BIASM == 2) val += bias[n];
        if (OUTM == 0) {
          ((float*)Cout)[(long)m * ldc + n] = val;
        } else {
          int W16 = 16 * Wout;
          int f = m / W16, r2 = m % W16;
          ((f16*)Cout)[(long)r2 * 4000 + f * 800 + n] = (f16)val;
        }
      }
    }
  }
}

// ---------------------------------------------------------------------------
// kv[b,d,e] = sum_s (w_lk cl_lsp + b_lk)[s,d] * (w_lv cl_lsp + b_lv)[s,e]
__global__ __launch_bounds__(256) void k_kv_partial(
    const float* __restrict__ cl, const float* __restrict__ wlk, const float* __restrict__ blk,
    const float* __restrict__ wlv, const float* __restrict__ blv, float* __restrict__ kvp) {
  __shared__ float s_wk[1600], s_wv[1600];
  __shared__ float s_cl[8][40], s_k[8][40], s_v[8][40];
  int t = threadIdx.x, chunk = blockIdx.x, b = blockIdx.y;
  for (int p = t; p < 1600; p += 256) { s_wk[p] = wlk[p]; s_wv[p] = wlv[p]; }
  float acc[7] = {0.f, 0.f, 0.f, 0.f, 0.f, 0.f, 0.f};
  for (int c8 = 0; c8 < 20; c8++) {
    int sb = chunk * 160 + c8 * 8;
    __syncthreads();
    for (int p = t; p < 320; p += 256) {
      int sl = p / 40, e = p % 40;
      s_cl[sl][e] = cl[(long)(sb + sl) * 640 + b * 40 + e];
    }
    __syncthreads();
    for (int p = t; p < 640; p += 256) {
      int half = p / 320, q = p % 320, sl = q / 40, d = q % 40;
      const float* w = half ? s_wv : s_wk;
      float r = half ? blv[d] : blk[d];
      for (int e = 0; e < 40; e++) r += w[d * 40 + e] * s_cl[sl][e];
      if (half) s_v[sl][d] = r; else s_k[sl][d] = r;
    }
    __syncthreads();
    int ai = 0;
    for (int p = t; p < 1600; p += 256, ai++) {
      int d = p / 40, e = p % 40;
      float a = acc[ai];
      for (int sl = 0; sl < 8; sl++) a += s_k[sl][d] * s_v[sl][e];
      acc[ai] = a;
    }
  }
  int ai = 0;
  for (int p = t; p < 1600; p += 256, ai++)
    kvp[((long)(b * 25 + chunk)) * 1600 + p] = acc[ai];
}

__global__ void k_kv_reduce(const float* __restrict__ kvp, float* __restrict__ kv) {
  int i = blockIdx.x * blockDim.x + threadIdx.x;
  if (i >= 16 * 1600) return;
  int b = i / 1600, p = i % 1600;
  float s = 0.f;
  for (int c = 0; c < 25; c++) s += kvp[((long)(b * 25 + c)) * 1600 + p];
  kv[i] = s;
}

// ---------------------------------------------------------------------------
// y[b] partial = sum_{s in chunk} [ sum_t v_t[s,:]·(q_t(s) @ kv[b]) + vsum[s,:]·lsp[b,s,:] ]
// NOTE: v was computed with wc scaled by 1024 -> divide out at write.
__global__ __launch_bounds__(256) void k_attn(
    const float* __restrict__ cl_g, const float* __restrict__ cl_p, const float* __restrict__ cl_c,
    const float* __restrict__ lsp32, const float* __restrict__ vmat, const float* __restrict__ kv,
    const float* __restrict__ wgq, const float* __restrict__ bgq,
    const float* __restrict__ wpq, const float* __restrict__ bpq,
    const float* __restrict__ wcq, const float* __restrict__ bcq,
    float* __restrict__ ypart) {
  __shared__ float s_kv[1600], s_wg[1600], s_wp[1200], s_wc[1600], s_bq[120];
  __shared__ float s_clg[16][40], s_clp[16][30], s_clc[16][40], s_lsp[16][40];
  __shared__ float s_v[16][120], s_q[16][120];
  __shared__ float s_red[256];
  int t = threadIdx.x, chunk = blockIdx.x, b = blockIdx.y;
  for (int p = t; p < 1600; p += 256) { s_kv[p] = kv[b * 1600 + p]; s_wg[p] = wgq[p]; s_wc[p] = wcq[p]; }
  for (int p = t; p < 1200; p += 256) s_wp[p] = wpq[p];
  if (t < 40) { s_bq[t] = bgq[t]; s_bq[40 + t] = bpq[t]; s_bq[80 + t] = bcq[t]; }
  float yacc = 0.f;
  for (int it = 0; it < 10; it++) {
    int sb = chunk * 160 + it * 16;
    __syncthreads();
    for (int p = t; p < 640; p += 256) {
      int sl = p / 40, e = p % 40;
      s_clg[sl][e] = cl_g[(long)(sb + sl) * 640 + b * 40 + e];
      s_clc[sl][e] = cl_c[(long)(sb + sl) * 640 + b * 40 + e];
      s_lsp[sl][e] = lsp32[((long)b * SEQN + sb + sl) * 40 + e];
    }
    for (int p = t; p < 480; p += 256) {
      int sl = p / 30, e = p % 30;
      s_clp[sl][e] = cl_p[(long)(sb + sl) * 480 + b * 30 + e];
    }
    for (int p = t; p < 1920; p += 256) {
      int sl = p / 120, l = p % 120;
      s_v[sl][l] = vmat[(long)(sb + sl) * 120 + l];
    }
    __syncthreads();
    for (int p = t; p < 1920; p += 256) {
      int sl = p / 120, j = p % 120, tt = j / 40, d = j % 40;
      float q = s_bq[j];
      if (tt == 0)      { for (int e = 0; e < 40; e++) q += s_wg[d * 40 + e] * s_clg[sl][e]; }
      else if (tt == 1) { for (int e = 0; e < 30; e++) q += s_wp[d * 30 + e] * s_clp[sl][e]; }
      else              { for (int e = 0; e < 40; e++) q += s_wc[d * 40 + e] * s_clc[sl][e]; }
      s_q[sl][j] = q;
    }
    __syncthreads();
    for (int p = t; p < 1920; p += 256) {
      int sl = p / 120, j = p % 120, tt = j / 40, eo = j % 40;
      float tmp = 0.f;
      for (int d = 0; d < 40; d++) tmp += s_q[sl][tt * 40 + d] * s_kv[d * 40 + eo];
      yacc += tmp * s_v[sl][tt * 40 + eo];
    }
    for (int p = t; p < 640; p += 256) {
      int sl = p / 40, d = p % 40;
      yacc += s_lsp[sl][d] * (s_v[sl][d] + s_v[sl][40 + d] + s_v[sl][80 + d]);
    }
  }
  __syncthreads();
  s_red[t] = yacc;
  __syncthreads();
  for (int o = 128; o > 0; o >>= 1) { if (t < o) s_red[t] += s_red[t + o]; __syncthreads(); }
  if (t == 0) ypart[b * 25 + chunk] = s_red[0] * (1.f / 1024.f);
}

// c1 partial: sum wc[o,l]*b_global[o]
__global__ __launch_bounds__(256) void k_c1(const float* __restrict__ wcls,
                                            const float* __restrict__ bg, float* __restrict__ c1p) {
  __shared__ float red[256];
  int t = threadIdx.x;
  float s = 0.f;
  for (long i = (long)blockIdx.x * 256 + t; i < 480000; i += (long)gridDim.x * 256)
    s += wcls[i] * bg[i / 120];
  red[t] = s; __syncthreads();
  for (int o = 128; o > 0; o >>= 1) { if (t < o) red[t] += red[t + o]; __syncthreads(); }
  if (t == 0) c1p[blockIdx.x] = red[0];
}

__global__ void k_final(const float* __restrict__ ypart, const float* __restrict__ c1p,
                        const float* __restrict__ bcls, const float* __restrict__ bnw,
                        const float* __restrict__ bnb, float* __restrict__ out) {
  int b = threadIdx.x;
  if (b >= 16) return;
  float c1 = bcls[0];
  for (int i = 0; i < 120; i++) c1 += c1p[i];
  float y = c1;
  for (int c = 0; c < 25; c++) y += ypart[b * 25 + c];
  y = y * (bnw[0] * rsqrtf(1.f + 1e-5f)) + bnb[0];
  out[b] = 1.f / (1.f + expf(-y));
}

// ---------------------------------------------------------------------------
extern "C" void kernel_launch(void* const* d_in, const int* in_sizes, int n_in,
                              void* d_out, int out_size, void* d_ws, size_t ws_size,
                              hipStream_t stream) {
  const int*   X        = (const int*)d_in[0];
  const float* emb      = (const float*)d_in[1];
  const float* w_dwc_l  = (const float*)d_in[2];
  const float* b_dwc_l  = (const float*)d_in[3];
  const float* w_dwc_o  = (const float*)d_in[4];
  const float* b_dwc_o  = (const float*)d_in[5];
  const float* w_local  = (const float*)d_in[6];
  const float* b_local  = (const float*)d_in[7];
  const float* w_global = (const float*)d_in[8];
  const float* b_global = (const float*)d_in[9];
  const float* w_gq = (const float*)d_in[10];
  const float* b_gq = (const float*)d_in[11];
  const float* w_cq = (const float*)d_in[12];
  const float* b_cq = (const float*)d_in[13];
  const float* w_pq = (const float*)d_in[14];
  const float* b_pq = (const float*)d_in[15];
  const float* w_lk = (const float*)d_in[16];
  const float* b_lk = (const float*)d_in[17];
  const float* w_lv = (const float*)d_in[18];
  const float* b_lv = (const float*)d_in[19];
  const float* w_cls = (const float*)d_in[20];
  const float* b_cls = (const float*)d_in[21];
  const float* bn_w = (const float*)d_in[22];
  const float* bn_b = (const float*)d_in[23];
  float* out = (float*)d_out;

  char* ws = (char*)d_ws;
  size_t off = 0;
  auto alloc = [&](size_t bytes) -> void* {
    off = (off + 255) & ~(size_t)255;
    void* p = ws + off; off += bytes; return p;
  };

  const size_t sz_pad40 = (size_t)800 * 7 * 16 * 42 * sizeof(f16);
  const size_t sz_pad30 = (size_t)800 * 7 * 16 * 32 * sizeof(f16);
  f16* pad_lsp = (f16*)alloc(sz_pad40);
  f16* pad_pit = (f16*)alloc(sz_pad30);
  f16* pad_cod = (f16*)alloc(sz_pad40);
  f16* pad_gai = (f16*)alloc(sz_pad40);
  float* lsp32 = (float*)alloc((size_t)16 * 4000 * 40 * 4);
  f16* wp_lsp = (f16*)alloc((size_t)896 * 7200 * 2);
  f16* wp_oth = (f16*)alloc((size_t)896 * 7200 * 2);
  f16* wlp    = (f16*)alloc((size_t)4096 * 4000 * 2);
  f16* wgT    = (f16*)alloc((size_t)4096 * 4000 * 2);
  f16* wcT    = (f16*)alloc((size_t)128 * 4000 * 2);
  f16* im2c   = (f16*)alloc((size_t)3200 * 7200 * 2);
  f16* co_lsp = (f16*)alloc((size_t)640 * 4000 * 2);
  f16* co_pit = (f16*)alloc((size_t)512 * 4000 * 2);
  f16* co_cod = (f16*)alloc((size_t)640 * 4000 * 2);
  f16* co_gai = (f16*)alloc((size_t)640 * 4000 * 2);
  float* cl_lsp = (float*)alloc((size_t)4000 * 640 * 4);
  float* cl_pit = (float*)alloc((size_t)4000 * 480 * 4);
  float* cl_cod = (float*)alloc((size_t)4000 * 640 * 4);
  float* cl_gai = (float*)alloc((size_t)4000 * 640 * 4);
  float* vmat = (float*)alloc((size_t)4000 * 120 * 4);
  float* kvp  = (float*)alloc((size_t)400 * 1600 * 4);
  float* kvb  = (float*)alloc((size_t)16 * 1600 * 4);
  float* ypart = (float*)alloc(400 * 4);
  float* c1p   = (float*)alloc(120 * 4);
  (void)ws_size; (void)in_sizes; (void)n_in; (void)out_size;

  // --- zero padded regions (borders / pad tails) ---
  hipMemsetAsync(pad_lsp, 0, sz_pad40, stream);
  hipMemsetAsync(pad_pit, 0, sz_pad30, stream);
  hipMemsetAsync(pad_cod, 0, sz_pad40, stream);
  hipMemsetAsync(pad_gai, 0, sz_pad40, stream);
  hipMemsetAsync(wp_lsp + (size_t)800 * 7200, 0, (size_t)96 * 7200 * 2, stream);
  hipMemsetAsync(wp_oth + (size_t)800 * 7200, 0, (size_t)96 * 7200 * 2, stream);
  hipMemsetAsync(wlp + (size_t)4000 * 4000, 0, (size_t)96 * 4000 * 2, stream);
  hipMemsetAsync(wgT + (size_t)4000 * 4000, 0, (size_t)96 * 4000 * 2, stream);
  hipMemsetAsync(wcT + (size_t)120 * 4000, 0, (size_t)8 * 4000 * 2, stream);
  hipMemsetAsync(co_pit + (size_t)480 * 4000, 0, (size_t)32 * 4000 * 2, stream);

  // --- weight packs ---
  k_cast_f16<<<4096, 256, 0, stream>>>(w_dwc_l, wp_lsp, 800 * 7200);
  k_cast_f16<<<4096, 256, 0, stream>>>(w_dwc_o, wp_oth, 800 * 7200);
  k_pack_wlocal<<<8192, 256, 0, stream>>>(w_local, wlp);
  {
    dim3 g(125, 125), blk(32, 8);
    k_transpose_cast<<<g, blk, 0, stream>>>(w_global, wgT, 4000, 4000, 4000, 1.f);
  }
  {
    dim3 g(4, 125), blk(32, 8);
    k_transpose_cast<<<g, blk, 0, stream>>>(w_cls, wcT, 4000, 120, 4000, 1024.f);
  }

  // --- gather ---
  k_gather<<<(BN * SEQN + 255) / 256, 256, 0, stream>>>(X, emb, pad_lsp, pad_pit, pad_cod, pad_gai, lsp32);

  // --- v = w_global^T @ (wc*1024) : [4000][120] ---
  {
    dim3 g(1, 32);
    k_gemm<0, 0><<<g, 256, 0, stream>>>(wgT, 4000, wcT, 4000, vmat, 120, nullptr,
                                        4000, 4000, 120, 0);
  }

  // --- per-branch: im2col -> conv GEMM -> w_local GEMM ---
  struct Br { f16* pad; int W, Mreal, Mpad, gy; const f16* wp; const float* bconv;
              f16* co; int Npad_co, Nreal_co; float* cl; };
  Br brs[4] = {
    {pad_lsp, 40, 3200, 3200, 25, wp_lsp, b_dwc_l, co_lsp, 640, 640, cl_lsp},
    {pad_pit, 30, 2400, 2432, 19, wp_oth, b_dwc_o, co_pit, 512, 480, cl_pit},
    {pad_cod, 40, 3200, 3200, 25, wp_oth, b_dwc_o, co_cod, 640, 640, cl_cod},
    {pad_gai, 40, 3200, 3200, 25, wp_oth, b_dwc_o, co_gai, 640, 640, cl_gai},
  };
  for (int i = 0; i < 4; i++) {
    Br& br = brs[i];
    int tot = br.Mpad * 800;
    k_im2col<<<(tot + 255) / 256, 256, 0, stream>>>(br.pad, im2c, br.W, br.Mreal, br.Mpad);
    {
      dim3 g(7, br.gy);  // N = 896 (padded 800), M = Mpad
      k_gemm<2, 2><<<g, 256, 0, stream>>>(im2c, 7200, br.wp, 7200, br.co, 4000,
                                          br.bconv, 7200, br.Mreal, 800, br.W);
    }
    {
      dim3 g(br.Npad_co / 128, 32);  // M = 4096 (padded 4000)
      k_gemm<0, 1><<<g, 256, 0, stream>>>(wlp, 4000, br.co, 4000, br.cl, br.Nreal_co,
                                          b_local, 4000, 4000, br.Nreal_co, 0);
    }
  }

  // --- kv ---
  {
    dim3 g(25, 16);
    k_kv_partial<<<g, 256, 0, stream>>>(cl_lsp, w_lk, b_lk, w_lv, b_lv, kvp);
  }
  k_kv_reduce<<<100, 256, 0, stream>>>(kvp, kvb);

  // --- c1 ---
  k_c1<<<120, 256, 0, stream>>>(w_cls, b_global, c1p);

  // --- attention collapse + reduction to y ---
  {
    dim3 g(25, 16);
    k_attn<<<g, 256, 0, stream>>>(cl_gai, cl_pit, cl_cod, lsp32, vmat, kvb,
                                  w_gq, b_gq, w_pq, b_pq, w_cq, b_cq, ypart);
  }

  // --- final sigmoid ---
  k_final<<<1, 64, 0, stream>>>(ypart, c1p, b_cls, bn_w, bn_b, out);
}

// Round 2
// 875.299 us; speedup vs baseline: 2.1077x; 2.1077x over previous
//
#include <hip/hip_runtime.h>
#include <hip/hip_bf16.h>

typedef _Float16 f16;
typedef __attribute__((ext_vector_type(8))) _Float16 half8;
typedef __attribute__((ext_vector_type(4))) float f32x4;

static const int BN = 16, SEQN = 4000;

// ---------------------------------------------------------------------------
__device__ __forceinline__ void gload_lds(f16* lds, const f16* g) {
  __builtin_amdgcn_global_load_lds((const __attribute__((address_space(1))) unsigned int*)g,
                                   (__attribute__((address_space(3))) unsigned int*)lds, 16, 0, 0);
}

// bijective XCD swizzle (m204)
__device__ __forceinline__ int xcd_swz(int orig, int nwg) {
  int q = nwg >> 3, r = nwg & 7, x = orig & 7, o = orig >> 3;
  return (x < r ? x * (q + 1) : r * (q + 1) + (x - r) * q) + o;
}

// ---------------------------------------------------------------------------
// weight packs
// conv weights -> wp[g_o][tap*800 + g_i], tap = df*3+de
__global__ void k_pack_wconv(const float* __restrict__ in, f16* __restrict__ out) {
  int i = blockIdx.x * blockDim.x + threadIdx.x;
  int stride = gridDim.x * blockDim.x;
  const int n = 800 * 7200;
  for (; i < n; i += stride) {
    int o = i / 7200, k = i % 7200;
    int tap = k / 800, gi = k % 800;
    out[i] = (f16)in[(long)o * 7200 + gi * 9 + tap];
  }
}

// out[s][f*800+g] = w_local[s][g*5+f]
__global__ void k_pack_wlocal(const float* __restrict__ in, f16* __restrict__ out) {
  int i = blockIdx.x * blockDim.x + threadIdx.x;
  int stride = gridDim.x * blockDim.x;
  const int n = 4000 * 4000;
  for (; i < n; i += stride) {
    int s = i / 4000, k = i % 4000;
    int f = k / 800, g = k % 800;
    out[i] = (f16)in[s * 4000 + g * 5 + f];
  }
}

// out[c*ldo + r] = in[r*C + c] * scale
__global__ void k_transpose_cast(const float* __restrict__ in, f16* __restrict__ out,
                                 int R, int C, int ldo, float scale) {
  __shared__ float tile[32][33];
  int c0 = blockIdx.x * 32, r0 = blockIdx.y * 32;
  for (int i = threadIdx.y; i < 32; i += 8) {
    int r = r0 + i, c = c0 + threadIdx.x;
    tile[i][threadIdx.x] = (r < R && c < C) ? in[(long)r * C + c] : 0.f;
  }
  __syncthreads();
  for (int i = threadIdx.y; i < 32; i += 8) {
    int c = c0 + i, r = r0 + threadIdx.x;
    if (c < C && r < R) out[(long)c * ldo + r] = (f16)(tile[threadIdx.x][i] * scale);
  }
}

// ---------------------------------------------------------------------------
// gather: P[fp][b][ep][g] layout (g innermost), coalesced over g
__global__ void k_gather(const int* __restrict__ X, const float* __restrict__ emb,
                         f16* __restrict__ P_lsp, f16* __restrict__ P_pit,
                         f16* __restrict__ P_cod, f16* __restrict__ P_gai,
                         float* __restrict__ lsp32) {
  const float scale[15] = {1.f,1.f,1.f,1.f,0.8f,0.512f,0.8f,0.64f,0.512f,0.64f,0.512f,0.8f,0.64f,0.512f,0.512f};
  const int br[15] = {0,0,0,0,1,1,2,2,3,3,1,2,2,3,3};
  const int po[15] = {0,1,2,3,0,1,0,1,0,2,2,2,3,1,3};
  int id = blockIdx.x * blockDim.x + threadIdx.x;
  if (id >= 15 * 16 * 5 * 800) return;
  int g = id % 800; int tmp = id / 800;
  int f = tmp % 5; tmp /= 5;
  int b = tmp % 16; int c = tmp / 16;
  int s = g * 5 + f;
  int idx = X[((long)b * SEQN + s) * 15 + c];
  const float* er = emb + (long)idx * 10;
  int t = br[c], p = po[c];
  f16* P = (t == 0) ? P_lsp : (t == 1) ? P_pit : (t == 2) ? P_cod : P_gai;
  int Wp = (t == 1) ? 32 : 42;
  f16* base = P + ((long)((f + 1) * 16 + b) * Wp + (1 + p * 10)) * 800 + g;
  float sc = scale[c];
#pragma unroll
  for (int j = 0; j < 10; j++) {
    float v = er[j] * sc;
    base[(long)j * 800] = (f16)v;
    if (t == 0) lsp32[((long)b * SEQN + s) * 40 + p * 10 + j] = v;
  }
}

// ---------------------------------------------------------------------------
// merged conv GEMM: M=12032 (lsp 3200 | pit 2432 | cod 3200 | gai 3200),
// N=896 (800 real), K=7200=(tap,gi). A is virtual im2col read from P.
// store: co[crow0 + (b*W+e)][f*800 + n] (f16, +bias[n])
__global__ __launch_bounds__(256) void k_gemm_conv(
    const f16* __restrict__ P_lsp, const f16* __restrict__ P_pit,
    const f16* __restrict__ P_cod, const f16* __restrict__ P_gai,
    const f16* __restrict__ wp_lsp, const f16* __restrict__ wp_oth,
    const float* __restrict__ bias_l, const float* __restrict__ bias_o,
    f16* __restrict__ co) {
  __shared__ __align__(16) f16 As[4096];
  __shared__ __align__(16) f16 Bs[4096];
  int lin = xcd_swz(blockIdx.x, 658);
  int nx = lin % 7, my = lin / 7;
  int m0 = my * 128, n0 = nx * 128;
  const f16* Pseg; const f16* wp; const float* bias;
  int soff, W, Mreal, crow0;
  if (m0 < 3200)      { soff = 0;    W = 40; Mreal = 3200; crow0 = 0;    Pseg = P_lsp; wp = wp_lsp; bias = bias_l; }
  else if (m0 < 5632) { soff = 3200; W = 30; Mreal = 2400; crow0 = 640;  Pseg = P_pit; wp = wp_oth; bias = bias_o; }
  else if (m0 < 8832) { soff = 5632; W = 40; Mreal = 3200; crow0 = 1120; Pseg = P_cod; wp = wp_oth; bias = bias_o; }
  else                { soff = 8832; W = 40; Mreal = 3200; crow0 = 1760; Pseg = P_gai; wp = wp_oth; bias = bias_o; }
  int Wp = W + 2, W16 = W * 16;
  int t = threadIdx.x;
  long aoff[2]; const f16* bptr[2];
#pragma unroll
  for (int q = 0; q < 2; q++) {
    int row = (q * 256 + t) >> 2;
    int ml = m0 + row - soff;
    if (ml >= Mreal) ml = 0;
    int f = ml / W16, rem = ml % W16;
    int b = rem / W, e = rem % W;
    aoff[q] = ((long)(f * 16 + b) * Wp + e) * 800 + (t & 3) * 8;
    bptr[q] = wp + (long)(n0 + row) * 7200 + (t & 3) * 8;
  }
  int lane = t & 63, wv = t >> 6;
  int wm = (wv >> 1) * 64, wn = (wv & 1) * 64;
  int l15 = lane & 15, kg = lane >> 4;
  f32x4 acc[4][4] = {};
  int df = 0, de = 0, g0 = 0, cnt = 0;
  for (int kt = 0; kt < 225; kt++) {
    long toff = ((long)(df * 16) * Wp + de) * 800 + g0;
    __syncthreads();
    gload_lds(&As[t * 8],        Pseg + aoff[0] + toff);
    gload_lds(&As[2048 + t * 8], Pseg + aoff[1] + toff);
    gload_lds(&Bs[t * 8],        bptr[0] + kt * 32);
    gload_lds(&Bs[2048 + t * 8], bptr[1] + kt * 32);
    __syncthreads();
    half8 av[4], bv[4];
#pragma unroll
    for (int i = 0; i < 4; i++) {
      av[i] = *(const half8*)(&As[(wm + i * 16 + l15) * 32 + kg * 8]);
      bv[i] = *(const half8*)(&Bs[(wn + i * 16 + l15) * 32 + kg * 8]);
    }
#pragma unroll
    for (int i = 0; i < 4; i++)
#pragma unroll
      for (int j = 0; j < 4; j++)
        acc[i][j] = __builtin_amdgcn_mfma_f32_16x16x32_f16(av[i], bv[j], acc[i][j], 0, 0, 0);
    g0 += 32; cnt++;
    if (cnt == 25) { cnt = 0; g0 = 0; de++; if (de == 3) { de = 0; df++; } }
  }
#pragma unroll
  for (int i = 0; i < 4; i++) {
    int mb = m0 + wm + i * 16 + kg * 4;
#pragma unroll
    for (int j = 0; j < 4; j++) {
      int n = n0 + wn + j * 16 + l15;
      if (n >= 800) continue;
      f32x4 d = acc[i][j];
      float bn = bias[n];
#pragma unroll
      for (int r = 0; r < 4; r++) {
        int ml = mb + r - soff;
        if (ml >= Mreal) continue;
        int f = ml / W16, r2 = ml % W16;
        co[(long)(crow0 + r2) * 4000 + f * 800 + n] = (f16)(d[r] + bn);
      }
    }
  }
}

// ---------------------------------------------------------------------------
// generic NT GEMM, global_load_lds staged, fp32 out. BIASM: 0 none, 1 bias[m].
template <int BIASM>
__global__ __launch_bounds__(256) void k_gemm_nt(
    const f16* __restrict__ A, int lda, const f16* __restrict__ Bm, int ldb,
    float* __restrict__ C, int ldc, const float* __restrict__ bias,
    int gx, int nwg, int nkt, long cslice, int Mreal, int Nreal, int Aclamp) {
  __shared__ __align__(16) f16 As[4096];
  __shared__ __align__(16) f16 Bs[4096];
  int lin = xcd_swz(blockIdx.x, nwg);
  int nx = lin % gx, my = lin / gx;
  int m0 = my * 128, n0 = nx * 128;
  int kt0 = blockIdx.y * nkt;
  C += (long)blockIdx.y * cslice;
  int t = threadIdx.x;
  const f16* aptr[2]; const f16* bptr[2];
#pragma unroll
  for (int q = 0; q < 2; q++) {
    int row = (q * 256 + t) >> 2;
    int ra = m0 + row; if (ra >= Aclamp) ra = Aclamp - 1;
    aptr[q] = A + (long)ra * lda + (long)kt0 * 32 + (t & 3) * 8;
    bptr[q] = Bm + (long)(n0 + row) * ldb + (long)kt0 * 32 + (t & 3) * 8;
  }
  int lane = t & 63, wv = t >> 6;
  int wm = (wv >> 1) * 64, wn = (wv & 1) * 64;
  int l15 = lane & 15, kg = lane >> 4;
  f32x4 acc[4][4] = {};
  for (int kt = 0; kt < nkt; kt++) {
    __syncthreads();
    gload_lds(&As[t * 8],        aptr[0] + kt * 32);
    gload_lds(&As[2048 + t * 8], aptr[1] + kt * 32);
    gload_lds(&Bs[t * 8],        bptr[0] + kt * 32);
    gload_lds(&Bs[2048 + t * 8], bptr[1] + kt * 32);
    __syncthreads();
    half8 av[4], bv[4];
#pragma unroll
    for (int i = 0; i < 4; i++) {
      av[i] = *(const half8*)(&As[(wm + i * 16 + l15) * 32 + kg * 8]);
      bv[i] = *(const half8*)(&Bs[(wn + i * 16 + l15) * 32 + kg * 8]);
    }
#pragma unroll
    for (int i = 0; i < 4; i++)
#pragma unroll
      for (int j = 0; j < 4; j++)
        acc[i][j] = __builtin_amdgcn_mfma_f32_16x16x32_f16(av[i], bv[j], acc[i][j], 0, 0, 0);
  }
#pragma unroll
  for (int i = 0; i < 4; i++) {
    int mb = m0 + wm + i * 16 + kg * 4;
#pragma unroll
    for (int j = 0; j < 4; j++) {
      int n = n0 + wn + j * 16 + l15;
      if (n >= Nreal) continue;
      f32x4 d = acc[i][j];
#pragma unroll
      for (int r = 0; r < 4; r++) {
        int m = mb + r;
        if (m >= Mreal) continue;
        float val = d[r];
        if (BIASM == 1) val += bias[m];
        C[(long)m * ldc + n] = val;
      }
    }
  }
}

__global__ void k_vred(const float* __restrict__ vp, float* __restrict__ v) {
  int i = blockIdx.x * blockDim.x + threadIdx.x;
  if (i >= 480000) return;
  float s = 0.f;
  for (int z = 0; z < 5; z++) s += vp[(long)z * 480000 + i];
  v[i] = s;
}

// ---------------------------------------------------------------------------
// kv[b,d,e] = sum_s K[s,d]*V[s,e], K/V from cl (ldc 2432, lsp at col 0)
__global__ __launch_bounds__(256) void k_kv_partial(
    const float* __restrict__ cl, const float* __restrict__ wlk, const float* __restrict__ blk,
    const float* __restrict__ wlv, const float* __restrict__ blv, float* __restrict__ kvp) {
  __shared__ float s_wk[1600], s_wv[1600];
  __shared__ float s_cl[8][40], s_k[8][40], s_v[8][40];
  int t = threadIdx.x, chunk = blockIdx.x, b = blockIdx.y;
  for (int p = t; p < 1600; p += 256) { s_wk[p] = wlk[p]; s_wv[p] = wlv[p]; }
  float acc[7] = {0.f, 0.f, 0.f, 0.f, 0.f, 0.f, 0.f};
  for (int c8 = 0; c8 < 20; c8++) {
    int sb = chunk * 160 + c8 * 8;
    __syncthreads();
    for (int p = t; p < 320; p += 256) {
      int sl = p / 40, e = p % 40;
      s_cl[sl][e] = cl[(long)(sb + sl) * 2432 + b * 40 + e];
    }
    __syncthreads();
    for (int p = t; p < 640; p += 256) {
      int half = p / 320, q = p % 320, sl = q / 40, d = q % 40;
      const float* w = half ? s_wv : s_wk;
      float r = half ? blv[d] : blk[d];
      for (int e = 0; e < 40; e++) r += w[d * 40 + e] * s_cl[sl][e];
      if (half) s_v[sl][d] = r; else s_k[sl][d] = r;
    }
    __syncthreads();
    int ai = 0;
    for (int p = t; p < 1600; p += 256, ai++) {
      int d = p / 40, e = p % 40;
      float a = acc[ai];
      for (int sl = 0; sl < 8; sl++) a += s_k[sl][d] * s_v[sl][e];
      acc[ai] = a;
    }
  }
  int ai = 0;
  for (int p = t; p < 1600; p += 256, ai++)
    kvp[((long)(b * 25 + chunk)) * 1600 + p] = acc[ai];
}

__global__ void k_kv_reduce(const float* __restrict__ kvp, float* __restrict__ kv) {
  int i = blockIdx.x * blockDim.x + threadIdx.x;
  if (i >= 16 * 1600) return;
  int b = i / 1600, p = i % 1600;
  float s = 0.f;
  for (int c = 0; c < 25; c++) s += kvp[((long)(b * 25 + c)) * 1600 + p];
  kv[i] = s;
}

// ---------------------------------------------------------------------------
__global__ __launch_bounds__(256) void k_attn(
    const float* __restrict__ cl, const float* __restrict__ lsp32,
    const float* __restrict__ vmat, const float* __restrict__ kv,
    const float* __restrict__ wgq, const float* __restrict__ bgq,
    const float* __restrict__ wpq, const float* __restrict__ bpq,
    const float* __restrict__ wcq, const float* __restrict__ bcq,
    float* __restrict__ ypart) {
  __shared__ float s_kv[1600], s_wg[1600], s_wp[1200], s_wc[1600], s_bq[120];
  __shared__ float s_clg[16][40], s_clp[16][30], s_clc[16][40], s_lsp[16][40];
  __shared__ float s_v[16][120], s_q[16][120];
  __shared__ float s_red[256];
  int t = threadIdx.x, chunk = blockIdx.x, b = blockIdx.y;
  for (int p = t; p < 1600; p += 256) { s_kv[p] = kv[b * 1600 + p]; s_wg[p] = wgq[p]; s_wc[p] = wcq[p]; }
  for (int p = t; p < 1200; p += 256) s_wp[p] = wpq[p];
  if (t < 40) { s_bq[t] = bgq[t]; s_bq[40 + t] = bpq[t]; s_bq[80 + t] = bcq[t]; }
  float yacc = 0.f;
  for (int it = 0; it < 10; it++) {
    int sb = chunk * 160 + it * 16;
    __syncthreads();
    for (int p = t; p < 640; p += 256) {
      int sl = p / 40, e = p % 40;
      s_clg[sl][e] = cl[(long)(sb + sl) * 2432 + 1760 + b * 40 + e];
      s_clc[sl][e] = cl[(long)(sb + sl) * 2432 + 1120 + b * 40 + e];
      s_lsp[sl][e] = lsp32[((long)b * SEQN + sb + sl) * 40 + e];
    }
    for (int p = t; p < 480; p += 256) {
      int sl = p / 30, e = p % 30;
      s_clp[sl][e] = cl[(long)(sb + sl) * 2432 + 640 + b * 30 + e];
    }
    for (int p = t; p < 1920; p += 256) {
      int sl = p / 120, l = p % 120;
      s_v[sl][l] = vmat[(long)(sb + sl) * 120 + l];
    }
    __syncthreads();
    for (int p = t; p < 1920; p += 256) {
      int sl = p / 120, j = p % 120, tt = j / 40, d = j % 40;
      float q = s_bq[j];
      if (tt == 0)      { for (int e = 0; e < 40; e++) q += s_wg[d * 40 + e] * s_clg[sl][e]; }
      else if (tt == 1) { for (int e = 0; e < 30; e++) q += s_wp[d * 30 + e] * s_clp[sl][e]; }
      else              { for (int e = 0; e < 40; e++) q += s_wc[d * 40 + e] * s_clc[sl][e]; }
      s_q[sl][j] = q;
    }
    __syncthreads();
    for (int p = t; p < 1920; p += 256) {
      int sl = p / 120, j = p % 120, tt = j / 40, eo = j % 40;
      float tmp = 0.f;
      for (int d = 0; d < 40; d++) tmp += s_q[sl][tt * 40 + d] * s_kv[d * 40 + eo];
      yacc += tmp * s_v[sl][tt * 40 + eo];
    }
    for (int p = t; p < 640; p += 256) {
      int sl = p / 40, d = p % 40;
      yacc += s_lsp[sl][d] * (s_v[sl][d] + s_v[sl][40 + d] + s_v[sl][80 + d]);
    }
  }
  __syncthreads();
  s_red[t] = yacc;
  __syncthreads();
  for (int o = 128; o > 0; o >>= 1) { if (t < o) s_red[t] += s_red[t + o]; __syncthreads(); }
  if (t == 0) ypart[b * 25 + chunk] = s_red[0] * (1.f / 1024.f);
}

__global__ __launch_bounds__(256) void k_c1(const float* __restrict__ wcls,
                                            const float* __restrict__ bg, float* __restrict__ c1p) {
  __shared__ float red[256];
  int t = threadIdx.x;
  float s = 0.f;
  for (long i = (long)blockIdx.x * 256 + t; i < 480000; i += (long)gridDim.x * 256)
    s += wcls[i] * bg[i / 120];
  red[t] = s; __syncthreads();
  for (int o = 128; o > 0; o >>= 1) { if (t < o) red[t] += red[t + o]; __syncthreads(); }
  if (t == 0) c1p[blockIdx.x] = red[0];
}

__global__ void k_final(const float* __restrict__ ypart, const float* __restrict__ c1p,
                        const float* __restrict__ bcls, const float* __restrict__ bnw,
                        const float* __restrict__ bnb, float* __restrict__ out) {
  int b = threadIdx.x;
  if (b >= 16) return;
  float c1 = bcls[0];
  for (int i = 0; i < 120; i++) c1 += c1p[i];
  float y = c1;
  for (int c = 0; c < 25; c++) y += ypart[b * 25 + c];
  y = y * (bnw[0] * rsqrtf(1.f + 1e-5f)) + bnb[0];
  out[b] = 1.f / (1.f + expf(-y));
}

// ---------------------------------------------------------------------------
extern "C" void kernel_launch(void* const* d_in, const int* in_sizes, int n_in,
                              void* d_out, int out_size, void* d_ws, size_t ws_size,
                              hipStream_t stream) {
  const int*   X        = (const int*)d_in[0];
  const float* emb      = (const float*)d_in[1];
  const float* w_dwc_l  = (const float*)d_in[2];
  const float* b_dwc_l  = (const float*)d_in[3];
  const float* w_dwc_o  = (const float*)d_in[4];
  const float* b_dwc_o  = (const float*)d_in[5];
  const float* w_local  = (const float*)d_in[6];
  const float* b_local  = (const float*)d_in[7];
  const float* w_global = (const float*)d_in[8];
  const float* b_global = (const float*)d_in[9];
  const float* w_gq = (const float*)d_in[10];
  const float* b_gq = (const float*)d_in[11];
  const float* w_cq = (const float*)d_in[12];
  const float* b_cq = (const float*)d_in[13];
  const float* w_pq = (const float*)d_in[14];
  const float* b_pq = (const float*)d_in[15];
  const float* w_lk = (const float*)d_in[16];
  const float* b_lk = (const float*)d_in[17];
  const float* w_lv = (const float*)d_in[18];
  const float* b_lv = (const float*)d_in[19];
  const float* w_cls = (const float*)d_in[20];
  const float* b_cls = (const float*)d_in[21];
  const float* bn_w = (const float*)d_in[22];
  const float* bn_b = (const float*)d_in[23];
  float* out = (float*)d_out;

  char* ws = (char*)d_ws;
  size_t off = 0;
  auto alloc = [&](size_t bytes) -> void* {
    off = (off + 255) & ~(size_t)255;
    void* p = ws + off; off += bytes; return p;
  };

  const size_t sz_p40 = (size_t)7 * 16 * 42 * 800 * 2;
  const size_t sz_p30 = (size_t)7 * 16 * 32 * 800 * 2;
  f16* P_lsp = (f16*)alloc(sz_p40);
  f16* P_pit = (f16*)alloc(sz_p30);
  f16* P_cod = (f16*)alloc(sz_p40);
  f16* P_gai = (f16*)alloc(sz_p40);
  float* lsp32 = (float*)alloc((size_t)16 * 4000 * 40 * 4);
  f16* wp_lsp = (f16*)alloc((size_t)896 * 7200 * 2);
  f16* wp_oth = (f16*)alloc((size_t)896 * 7200 * 2);
  f16* wlp    = (f16*)alloc((size_t)4000 * 4000 * 2);
  f16* wgT    = (f16*)alloc((size_t)4000 * 4000 * 2);
  f16* wcT    = (f16*)alloc((size_t)128 * 4000 * 2);
  f16* co_all = (f16*)alloc((size_t)2432 * 4000 * 2);
  float* cl   = (float*)alloc((size_t)4000 * 2432 * 4);
  float* vpart = (float*)alloc((size_t)5 * 480000 * 4);
  float* vmat  = (float*)alloc((size_t)480000 * 4);
  float* kvp  = (float*)alloc((size_t)400 * 1600 * 4);
  float* kvb  = (float*)alloc((size_t)16 * 1600 * 4);
  float* ypart = (float*)alloc(400 * 4);
  float* c1p   = (float*)alloc(120 * 4);
  (void)ws_size; (void)in_sizes; (void)n_in; (void)out_size;

  // zero conv-pad borders
  hipMemsetAsync(P_lsp, 0, sz_p40, stream);
  hipMemsetAsync(P_pit, 0, sz_p30, stream);
  hipMemsetAsync(P_cod, 0, sz_p40, stream);
  hipMemsetAsync(P_gai, 0, sz_p40, stream);

  // weight packs
  k_pack_wconv<<<2048, 256, 0, stream>>>(w_dwc_l, wp_lsp);
  k_pack_wconv<<<2048, 256, 0, stream>>>(w_dwc_o, wp_oth);
  k_pack_wlocal<<<8192, 256, 0, stream>>>(w_local, wlp);
  {
    dim3 g(125, 125), blk(32, 8);
    k_transpose_cast<<<g, blk, 0, stream>>>(w_global, wgT, 4000, 4000, 4000, 1.f);
  }
  {
    dim3 g(4, 125), blk(32, 8);
    k_transpose_cast<<<g, blk, 0, stream>>>(w_cls, wcT, 4000, 120, 4000, 1024.f);
  }

  // gather
  k_gather<<<(15 * 16 * 5 * 800 + 255) / 256, 256, 0, stream>>>(
      X, emb, P_lsp, P_pit, P_cod, P_gai, lsp32);

  // v = w_global^T @ (wc*1024), split-K 5 slices + reduce
  {
    dim3 g(32, 5);
    k_gemm_nt<0><<<g, 256, 0, stream>>>(wgT, 4000, wcT, 4000, vpart, 120, nullptr,
                                        1, 32, 25, 480000, 4000, 120, 4000);
  }
  k_vred<<<1875, 256, 0, stream>>>(vpart, vmat);

  // merged conv GEMM (all 4 branches, virtual im2col)
  k_gemm_conv<<<658, 256, 0, stream>>>(P_lsp, P_pit, P_cod, P_gai,
                                       wp_lsp, wp_oth, b_dwc_l, b_dwc_o, co_all);

  // merged w_local GEMM: cl[s][branch-col], ldc 2432
  k_gemm_nt<1><<<608, 256, 0, stream>>>(wlp, 4000, co_all, 4000, cl, 2432, b_local,
                                        19, 608, 125, 0, 4000, 2400, 4000);

  // kv
  {
    dim3 g(25, 16);
    k_kv_partial<<<g, 256, 0, stream>>>(cl, w_lk, b_lk, w_lv, b_lv, kvp);
  }
  k_kv_reduce<<<100, 256, 0, stream>>>(kvp, kvb);

  // c1
  k_c1<<<120, 256, 0, stream>>>(w_cls, b_global, c1p);

  // attention collapse
  {
    dim3 g(25, 16);
    k_attn<<<g, 256, 0, stream>>>(cl, lsp32, vmat, kvb,
                                  w_gq, b_gq, w_pq, b_pq, w_cq, b_cq, ypart);
  }

  k_final<<<1, 64, 0, stream>>>(ypart, c1p, b_cls, bn_w, bn_b, out);
}